// Round 5
// baseline (325.378 us; speedup 1.0000x reference)
//
#include <hip/hip_runtime.h>
#include <math.h>

#define R_ 4
#define B_ 16
#define HQ_ 32
#define HKV_ 2
#define G_ 16
#define D_ 128
#define S_ 32
#define L_ 2048
#define P_ 32768
#define TS_ 64
#define KSTR 136   // halves per k_s/q_s row (272B, 16B-mult)
#define VSTR 72    // halves per v2_sT/p2_sT row (144B, 16B-mult)
#define NEGINF (-INFINITY)
#define SENT (-1e30f)

typedef _Float16 h2 __attribute__((ext_vector_type(2)));
typedef _Float16 h4 __attribute__((ext_vector_type(4)));
typedef _Float16 h8 __attribute__((ext_vector_type(8)));
typedef float    f4v __attribute__((ext_vector_type(4)));

// ws layout:
//   lse_split [R][B][HKV][S][G]   float = 65536 f
//   chunk_m   [R][B][HKV][S][G]   float = 65536 f
//   chunk_acc [R][B][HKV][S][D][G] half = 8388608 h  (d-major!)

__global__ __launch_bounds__(256, 3) void fd_stage1(
    const float* __restrict__ q, const float* __restrict__ kc,
    const float* __restrict__ vc, const int* __restrict__ bt,
    const int* __restrict__ lens,
    float* __restrict__ lse_split, float* __restrict__ chunk_m,
    _Float16* __restrict__ chunk_acc)
{
  const int t   = threadIdx.x;
  const int blk = blockIdx.x;
  const int s   = blk & 31;
  const int hkv = (blk >> 5) & 1;
  const int b   = (blk >> 6) & 15;
  const int r   = blk >> 10;

  const int len = lens[r*B_ + b];
  const int per = (len + 31) >> 5;        // ceil(len/32), 2..64
  const int n0  = s*per;
  const int tn  = min(per, len - n0);     // block-uniform

  float* lse_out   = lse_split + ((r*B_ + b)*HKV_ + hkv)*(S_*G_);
  const int cmbase = (((r*B_ + b)*HKV_ + hkv)*S_ + s)*G_;
  _Float16* ca2 = chunk_acc + (size_t)(((r*B_ + b)*HKV_ + hkv)*S_ + s)*(D_*G_);

  if (tn <= 0) {                          // empty split: -inf lse/m, zero acc
    if (t < G_) { lse_out[s*G_ + t] = NEGINF; chunk_m[cmbase + t] = NEGINF; }
    h8 z = {(_Float16)0,(_Float16)0,(_Float16)0,(_Float16)0,
            (_Float16)0,(_Float16)0,(_Float16)0,(_Float16)0};
    ((h8*)ca2)[t] = z;                    // 256 thr x 8 halves = D_*G_
    return;
  }

  __shared__ __align__(16) _Float16 q_s[G_][KSTR];
  __shared__ __align__(16) _Float16 k_s[TS_][KSTR];
  __shared__ __align__(16) _Float16 v2_sT[D_][VSTR];   // [d][row] transposed
  __shared__ __align__(16) _Float16 p2_sT[G_][VSTR];   // [g][row] transposed
  __shared__ float red_m[4][G_];
  __shared__ float red_s[4][G_];
  __shared__ int   page_s[TS_];

  const int* btb   = bt + (r*B_ + b)*L_;
  const int kvbase = r*(P_*HKV_*D_) + hkv*D_;

  if (t < TS_) page_s[t] = (t < tn) ? btb[n0 + t] : 0;
  __syncthreads();

  // --- stage K (fp32 -> fp16), row-major: 8 rows in flight, 32 lanes x float4
  {
    const int lane32 = t & 31, r0 = t >> 5;
    #pragma unroll
    for (int it = 0; it < 8; ++it) {
      const int row = r0 + 8*it;
      if (row < tn) {
        const float4 v = *(const float4*)&kc[kvbase + page_s[row]*(HKV_*D_) + lane32*4];
        h4 hv; hv.x=(_Float16)v.x; hv.y=(_Float16)v.y; hv.z=(_Float16)v.z; hv.w=(_Float16)v.w;
        *(h4*)&k_s[row][lane32*4] = hv;
      }
    }
  }

  // --- stage V transposed (fp32 -> fp16): lane owns dim-pair d2 (ALL 128 dims
  //     covered: d2 = t&63), 4-row groups, zero-filled past tn
  {
    const int d2  = t & 63;                // dims {2*d2, 2*d2+1}, 0..127
    const int rg0 = t >> 6;                // 0..3
    #pragma unroll
    for (int it = 0; it < 4; ++it) {
      const int row = (rg0 + 4*it)*4;      // 0,4,...,60
      float2 v0 = make_float2(0.f,0.f), v1 = v0, v2 = v0, v3 = v0;
      if (row     < tn) v0 = *(const float2*)&vc[kvbase + page_s[row  ]*(HKV_*D_) + 2*d2];
      if (row + 1 < tn) v1 = *(const float2*)&vc[kvbase + page_s[row+1]*(HKV_*D_) + 2*d2];
      if (row + 2 < tn) v2 = *(const float2*)&vc[kvbase + page_s[row+2]*(HKV_*D_) + 2*d2];
      if (row + 3 < tn) v3 = *(const float2*)&vc[kvbase + page_s[row+3]*(HKV_*D_) + 2*d2];
      h4 a; a.x=(_Float16)v0.x; a.y=(_Float16)v1.x; a.z=(_Float16)v2.x; a.w=(_Float16)v3.x;
      h4 c; c.x=(_Float16)v0.y; c.y=(_Float16)v1.y; c.z=(_Float16)v2.y; c.w=(_Float16)v3.y;
      *(h4*)&v2_sT[2*d2    ][row] = a;
      *(h4*)&v2_sT[2*d2 + 1][row] = c;
    }
  }

  // --- stage Q (fp32 -> fp16)
  {
    const float* qb = q + (b*HQ_ + hkv*G_)*D_;
    int f4i = t;
    #pragma unroll
    for (int i = 0; i < 2; ++i, f4i += 256) {
      const int g = f4i >> 5, dd = (f4i & 31)*4;
      const float4 v = *(const float4*)&qb[g*D_ + dd];
      h4 hv; hv.x=(_Float16)v.x; hv.y=(_Float16)v.y; hv.z=(_Float16)v.z; hv.w=(_Float16)v.w;
      *(h4*)&q_s[g][dd] = hv;
    }
  }
  __syncthreads();

  // --- QK^T via MFMA: wave w owns k-row tile [16w, 16w+16)
  const int w    = t >> 6;
  const int lane = t & 63;
  const int ln   = lane & 15;
  const int quad = lane >> 4;
  const int nrow = w*16 + ln;              // this lane's k-row (C/D col)

  f4v acc = {0.f, 0.f, 0.f, 0.f};
  #pragma unroll
  for (int ks = 0; ks < 4; ++ks) {
    const h8 af = *(const h8*)&q_s[ln][ks*32 + quad*8];        // A[m=g][k]
    const h8 bf = *(const h8*)&k_s[nrow][ks*32 + quad*8];      // B[k][n=row]
    acc = __builtin_amdgcn_mfma_f32_16x16x32_f16(af, bf, acc, 0, 0, 0);
  }

  const float sc = 0.08838834764831845f;   // 128^-0.5
  const bool vld = (nrow < tn);
  float sv[4], pm[4];
  #pragma unroll
  for (int i = 0; i < 4; ++i) { sv[i] = vld ? acc[i]*sc : SENT; pm[i] = sv[i]; }
  #pragma unroll
  for (int off = 1; off < 16; off <<= 1) {
    #pragma unroll
    for (int i = 0; i < 4; ++i) pm[i] = fmaxf(pm[i], __shfl_xor(pm[i], off));
  }
  float ts[4];
  #pragma unroll
  for (int i = 0; i < 4; ++i) ts[i] = __expf(sv[i] - pm[i]);   // invalid -> ~0
  #pragma unroll
  for (int off = 1; off < 16; off <<= 1) {
    #pragma unroll
    for (int i = 0; i < 4; ++i) ts[i] += __shfl_xor(ts[i], off);
  }
  if (ln == 0) {
    #pragma unroll
    for (int i = 0; i < 4; ++i) {
      red_m[w][quad*4 + i] = pm[i];
      red_s[w][quad*4 + i] = ts[i];
    }
  }
  __syncthreads();

  // --- cross-wave softmax combine (per head), exact per-split lse
  float pmg[4];
  #pragma unroll
  for (int i = 0; i < 4; ++i) {
    const int hd = quad*4 + i;
    const float m0 = red_m[0][hd], m1 = red_m[1][hd];
    const float m2 = red_m[2][hd], m3 = red_m[3][hd];
    const float mg = fmaxf(fmaxf(m0, m1), fmaxf(m2, m3));
    pmg[i] = mg;
    if (w == 0 && ln == 0) {
      const float ps = red_s[0][hd]*__expf(m0 - mg) + red_s[1][hd]*__expf(m1 - mg)
                     + red_s[2][hd]*__expf(m2 - mg) + red_s[3][hd]*__expf(m3 - mg);
      lse_out[s*G_ + hd]  = mg + __logf(ps);
      chunk_m[cmbase + hd] = mg;
    }
  }
  // p = exp(s - m), fp16, transposed [g][row]; invalid rows -> 0
  #pragma unroll
  for (int i = 0; i < 4; ++i)
    p2_sT[quad*4 + i][nrow] = (_Float16)__expf(sv[i] - pmg[i]);
  __syncthreads();

  // --- PV via MFMA: wave w owns d-tiles {2w, 2w+1}
  const int KS2 = (tn + 31) >> 5;          // 1..2 k-steps of 32 rows
  f4v o0 = {0.f,0.f,0.f,0.f}, o1 = {0.f,0.f,0.f,0.f};
  const int dc0 = (2*w)*16 + ln, dc1 = (2*w + 1)*16 + ln;
  for (int ks = 0; ks < KS2; ++ks) {
    const h8 pa  = *(const h8*)&p2_sT[ln][ks*32 + quad*8];     // A[m=g][k=row]
    const h8 vb0 = *(const h8*)&v2_sT[dc0][ks*32 + quad*8];    // B[k=row][n=d]
    const h8 vb1 = *(const h8*)&v2_sT[dc1][ks*32 + quad*8];
    o0 = __builtin_amdgcn_mfma_f32_16x16x32_f16(pa, vb0, o0, 0, 0, 0);
    o1 = __builtin_amdgcn_mfma_f32_16x16x32_f16(pa, vb1, o1, 0, 0, 0);
  }
  // C/D: lane holds heads quad*4..+3 (regs) at d-col dc; ca2 is [d][g] -> h4 pack
  h4 w0; w0.x=(_Float16)o0[0]; w0.y=(_Float16)o0[1]; w0.z=(_Float16)o0[2]; w0.w=(_Float16)o0[3];
  h4 w1; w1.x=(_Float16)o1[0]; w1.y=(_Float16)o1[1]; w1.z=(_Float16)o1[2]; w1.w=(_Float16)o1[3];
  *(h4*)&ca2[dc0*G_ + quad*4] = w0;
  *(h4*)&ca2[dc1*G_ + quad*4] = w1;
}

__global__ __launch_bounds__(128) void fd_stage2(
    const float* __restrict__ lse_split, const float* __restrict__ chunk_m,
    const _Float16* __restrict__ chunk_acc, float* __restrict__ out)
{
  const int bh  = blockIdx.x;          // b*32 + h
  const int b   = bh >> 5, h = bh & 31;
  const int hkv = h >> 4, g = h & 15;
  const int d   = threadIdx.x;

  float m_r[R_], lse_r[R_];
  #pragma unroll
  for (int r = 0; r < R_; ++r) {
    const float* ls = lse_split + ((r*B_ + b)*HKV_ + hkv)*(S_*G_) + g;
    float m = NEGINF;
    #pragma unroll 8
    for (int s2 = 0; s2 < S_; ++s2) m = fmaxf(m, ls[s2*G_]);
    float sum = 0.f;
    #pragma unroll 8
    for (int s2 = 0; s2 < S_; ++s2) sum += __expf(ls[s2*G_] - m);
    m_r[r]   = m;
    lse_r[r] = m + __logf(sum);
  }
  const float M = fmaxf(fmaxf(lse_r[0], lse_r[1]), fmaxf(lse_r[2], lse_r[3]));
  float denom = 0.f, o = 0.f;
  #pragma unroll
  for (int r = 0; r < R_; ++r) {
    const float w = __expf(lse_r[r] - M);
    denom += w;
    const float* cm = chunk_m + (((r*B_ + b)*HKV_ + hkv)*S_)*G_ + g;
    const _Float16* ca = chunk_acc
        + (size_t)(((r*B_ + b)*HKV_ + hkv)*S_)*(D_*G_) + d*G_ + g;   // d-major
    float a = 0.f;
    #pragma unroll 8
    for (int c = 0; c < S_; ++c)
      a += __expf(cm[c*G_] - m_r[r]) * (float)ca[(size_t)c*(D_*G_)];
    o += w * a;   // faithful: acc_r UNNORMALIZED, weighted by exp(lse_r - M)
  }
  out[(size_t)bh*D_ + d] = o / denom;
}

extern "C" void kernel_launch(void* const* d_in, const int* in_sizes, int n_in,
                              void* d_out, int out_size, void* d_ws, size_t ws_size,
                              hipStream_t stream) {
  const float* q   = (const float*)d_in[0];
  const float* kc  = (const float*)d_in[1];
  const float* vc  = (const float*)d_in[2];
  const int*   bt  = (const int*)d_in[3];
  const int*   len = (const int*)d_in[4];
  float* out = (float*)d_out;
  float* ws  = (float*)d_ws;

  const size_t lse_f = (size_t)R_*B_*HKV_*S_*G_;   // 65536
  float*    lse_split = ws;
  float*    chunk_m   = ws + lse_f;
  _Float16* chunk_acc = (_Float16*)(ws + 2*lse_f);

  fd_stage1<<<dim3(R_*B_*HKV_*S_), dim3(256), 0, stream>>>(
      q, kc, vc, bt, len, lse_split, chunk_m, chunk_acc);
  fd_stage2<<<dim3(B_*HQ_), dim3(128), 0, stream>>>(
      lse_split, chunk_m, chunk_acc, out);
}